// Round 4
// baseline (28.943 us; speedup 1.0000x reference)
//
#include <hip/hip_runtime.h>
#include <math.h>

#define NV 65536
#define NE 4096
#define NP 4096
#define NT 512
#define SENTF 1000000000.0f
#define BIGF 1e30f

// ---------------- wave(64) reduction helpers ----------------
__device__ __forceinline__ float waveMinF(float v) {
    #pragma unroll
    for (int o = 32; o; o >>= 1) v = fminf(v, __shfl_xor(v, o, 64));
    return v;
}
__device__ __forceinline__ float waveMaxF(float v) {
    #pragma unroll
    for (int o = 32; o; o >>= 1) v = fmaxf(v, __shfl_xor(v, o, 64));
    return v;
}
__device__ __forceinline__ int waveSumI(int v) {
    #pragma unroll
    for (int o = 32; o; o >>= 1) v += __shfl_xor(v, o, 64);
    return v;
}
__device__ __forceinline__ int waveMinI(int v) {
    #pragma unroll
    for (int o = 32; o; o >>= 1) v = min(v, __shfl_xor(v, o, 64));
    return v;
}

// ---------------- kernel 1: per-edge params (packed) + table repack ----------------
__global__ void prep_kernel(const float* __restrict__ verts,
                            const int*   __restrict__ edges,
                            const float* __restrict__ tab,
                            float*  __restrict__ ea,  float*  __restrict__ eb,
                            float2* __restrict__ pk2, float4* __restrict__ pk4,
                            float4* __restrict__ tb4) {
    int e = blockIdx.x * blockDim.x + threadIdx.x;
    if (e < NT) {
        const float* r = tab + 7 * e;
        tb4[e] = make_float4(r[3], r[4], r[5], r[6]);
    }
    if (e >= NE) return;
    int i0 = edges[2 * e + 0];
    int i1 = edges[2 * e + 1];
    float x0 = verts[3 * i0 + 0], y0 = verts[3 * i0 + 1];
    float x1 = verts[3 * i1 + 0], y1 = verts[3 * i1 + 1];
    float a = (y0 - y1) / (x0 - x1);
    float b = y0 - a * x0;
    ea[e] = a; eb[e] = b;
    pk2[e] = make_float2(fminf(x0, x1), fmaxf(x0, x1));
    pk4[e] = make_float4(fminf(y0, y1), fmaxf(y0, y1), 1.0f / a, b);  // reciprocal hoisted
}

// ---------------- kernel 2: 16 waves/block, ONE wave per point, pk4 staged in LDS ----------------
__global__ __launch_bounds__(1024) void point_kernel(
        const float*  __restrict__ verts,
        const int*    __restrict__ listAll,
        const float*  __restrict__ ea,  const float*  __restrict__ eb,
        const float2* __restrict__ pk2, const float4* __restrict__ pk4,
        const float4* __restrict__ tb4,
        float* __restrict__ mOut, int* __restrict__ validOut) {
    __shared__ float4 sE[NE];   // 64 KB: (ymn, ymx, 1/a, b) per edge

    int tid  = threadIdx.x;
    int lane = tid & 63;
    int wid  = tid >> 6;              // 0..15
    int p    = blockIdx.x * 16 + wid; // one wave per point

    // ---- issue staging loads first (latency hides under phase 1) ----
    float4 r0 = pk4[tid];
    float4 r1 = pk4[1024 + tid];
    float4 r2 = pk4[2048 + tid];
    float4 r3 = pk4[3072 + tid];

    int   vi = listAll[p];
    float px = verts[3 * vi + 0];
    float py = verts[3 * vi + 1];

    // ---- phase 1: first edge with px strictly inside (xmn, xmx) — early exit ----
    int minIdx = NE;
    for (int it = 0; it < NE / 64; ++it) {
        int e = it * 64 + lane;
        float2 q = pk2[e];
        bool hit = (px > q.x) && (px < q.y);
        if (hit) minIdx = e;
        if (__any(hit)) break;
    }
    minIdx = waveMinI(minIdx);
    int idx = (minIdx >= NE) ? (NE - 1) : minIdx;

    float exposeY = ea[idx] * px + eb[idx];   // true-divide slope path (bit-exact)
    float L1 = fabsf(py - exposeY);
    float cy = 0.5f * (py + exposeY);
    float cx = px;

    // ---- complete staging, then barrier ----
    sE[tid]        = r0;
    sE[1024 + tid] = r1;
    sE[2048 + tid] = r2;
    sE[3072 + tid] = r3;
    __syncthreads();

    // ---- phase 2: branchless condB reductions over ALL edges from LDS ----
    int   n = 0, hasS = 0, hasI = 0;
    float xallmx = -SENTF, xallmn = SENTF;
    float xs = SENTF, xinf = -SENTF;
    #pragma unroll 8
    for (int it = 0; it < NE / 64; ++it) {
        float4 q = sE[it * 64 + lane];        // (ymn, ymx, 1/a, b)
        bool  c  = (cy > q.x) && (cy < q.y);
        float xi = (cy - q.w) * q.z;
        n += c ? 1 : 0;
        xallmx = fmaxf(xallmx, c ? xi : -SENTF);
        xallmn = fminf(xallmn, c ? xi :  SENTF);
        bool sp  = c && (xi >= cx);
        bool in_ = c && (xi <  cx);
        xs   = fminf(xs,   sp  ? xi :  SENTF);
        xinf = fmaxf(xinf, in_ ? xi : -SENTF);
        hasS |= sp ? 1 : 0;
        hasI |= in_ ? 1 : 0;
    }
    int packed = n | (hasS << 16) | (hasI << 24);
    packed = waveSumI(packed);
    xallmx = waveMaxF(xallmx);
    xallmn = waveMinF(xallmn);
    xs     = waveMinF(xs);
    xinf   = waveMaxF(xinf);
    n    = packed & 0xFFFF;
    hasS = (packed >> 16) & 0xFF;
    hasI = (packed >> 24) & 0xFF;

    bool valid = (n == 2) || ((n > 2) && (hasS > 0) && (hasI > 0));
    float dx = (n == 2) ? (xallmx - xallmn) : (xs - xinf);
    float L2 = fabsf(dx);
    float d1 = fabsf(cy - 1.0f);
    float d2 = fabsf(px - 1.0f);

    // ---- phase 3: min over all 512 table rows (global float4, L1-hot) ----
    float pm = INFINITY;
    #pragma unroll
    for (int k = 0; k < NT / 64; ++k) {
        float4 r = tb4[k * 64 + lane];
        float al = fabsf(L1 - r.x) + fabsf(L2 - r.y) +
                   fabsf(d1 - r.z) + fabsf(d2 - r.w);
        pm = fminf(pm, al);
    }
    pm = waveMinF(pm);

    if (lane == 0) {
        mOut[p]     = valid ? pm : BIGF;
        validOut[p] = valid ? 1 : 0;
    }
}

// ---------------- kernel 3: cummin + masked sum (single block, shuffle scans) ----------------
__global__ __launch_bounds__(1024) void scan_kernel(const float* __restrict__ m,
                                                    const int*   __restrict__ valid,
                                                    float* __restrict__ out) {
    __shared__ float wAgg[16];
    __shared__ float wSum[16];
    int t = threadIdx.x;
    int lane = t & 63, wid = t >> 6;

    float v[4]; int vl[4];
    #pragma unroll
    for (int j = 0; j < 4; j++) { v[j] = m[4 * t + j]; vl[j] = valid[4 * t + j]; }
    float cmin = fminf(fminf(v[0], v[1]), fminf(v[2], v[3]));

    // inclusive wave min-scan via shfl_up
    float inc = cmin;
    #pragma unroll
    for (int o = 1; o < 64; o <<= 1) {
        float u = __shfl_up(inc, o, 64);
        if (lane >= o) inc = fminf(inc, u);
    }
    if (lane == 63) wAgg[wid] = inc;
    __syncthreads();

    float wavePrefix = INFINITY;
    for (int i = 0; i < wid; i++) wavePrefix = fminf(wavePrefix, wAgg[i]);
    float excl = __shfl_up(inc, 1, 64);
    if (lane == 0) excl = INFINITY;
    float run = fminf(wavePrefix, excl);

    float sum = 0.0f;
    #pragma unroll
    for (int j = 0; j < 4; j++) {
        run = fminf(run, v[j]);
        if (vl[j]) sum += run;
    }
    #pragma unroll
    for (int o = 32; o; o >>= 1) sum += __shfl_xor(sum, o, 64);
    if (lane == 0) wSum[wid] = sum;
    __syncthreads();
    if (t == 0) {
        float s = 0.0f;
        for (int i = 0; i < 16; i++) s += wSum[i];
        out[0] = s;
    }
}

extern "C" void kernel_launch(void* const* d_in, const int* in_sizes, int n_in,
                              void* d_out, int out_size, void* d_ws, size_t ws_size,
                              hipStream_t stream) {
    const float* verts   = (const float*)d_in[0];
    const float* tab     = (const float*)d_in[1];
    const int*   edges   = (const int*)d_in[2];
    const int*   listAll = (const int*)d_in[3];

    // workspace layout (16-B aligned first)
    char* ws = (char*)d_ws;
    float4* pk4 = (float4*)ws;                     ws += NE * sizeof(float4);
    float4* tb4 = (float4*)ws;                     ws += NT * sizeof(float4);
    float2* pk2 = (float2*)ws;                     ws += NE * sizeof(float2);
    float*  ea  = (float*)ws;                      ws += NE * sizeof(float);
    float*  eb  = (float*)ws;                      ws += NE * sizeof(float);
    float*  mArr= (float*)ws;                      ws += NP * sizeof(float);
    int*    vArr= (int*)ws;

    prep_kernel<<<(NE + 255) / 256, 256, 0, stream>>>(verts, edges, tab, ea, eb, pk2, pk4, tb4);
    point_kernel<<<NP / 16, 1024, 0, stream>>>(verts, listAll, ea, eb, pk2, pk4, tb4, mArr, vArr);
    scan_kernel<<<1, 1024, 0, stream>>>(mArr, vArr, (float*)d_out);
}